// Round 15
// baseline (168.301 us; speedup 1.0000x reference)
//
#include <hip/hip_runtime.h>
#include <stdint.h>
#include <type_traits>

typedef unsigned short u16;
using short8  = __attribute__((ext_vector_type(8))) short;
using ushort8 = __attribute__((ext_vector_type(8))) unsigned short;
using floatx4 = __attribute__((ext_vector_type(4))) float;

#define IC(n) (std::integral_constant<int, (n)>())

__device__ __forceinline__ u16 f2bf(float f) {
    unsigned u = __float_as_uint(f);
    u += 0x7fff + ((u >> 16) & 1);   // round-to-nearest-even
    return (u16)(u >> 16);
}
__device__ __forceinline__ float bf2f(u16 h) {
    return __uint_as_float(((unsigned)h) << 16);
}

// async global->LDS, 16B per lane (global_load_lds_dwordx4)
__device__ __forceinline__ void gload_lds16(const void* g, void* l) {
    auto gp = reinterpret_cast<const __attribute__((address_space(1))) unsigned int*>(
        reinterpret_cast<uintptr_t>(g));
    auto lp = reinterpret_cast<__attribute__((address_space(3))) unsigned int*>(
        reinterpret_cast<uintptr_t>(l));
    __builtin_amdgcn_global_load_lds(gp, lp, 16, 0, 0);
}

// 1) convert x f32 -> bf16 ----------------------------------------------------
__global__ __launch_bounds__(256) void cvt_f32_bf16_kernel(
        const float* __restrict__ in, u16* __restrict__ out) {
    long i = ((long)blockIdx.x * 256 + threadIdx.x) * 4;
    float4 v = *(const float4*)(in + i);
    ushort4 o;
    o.x = f2bf(v.x); o.y = f2bf(v.y); o.z = f2bf(v.z); o.w = f2bf(v.w);
    *(ushort4*)(out + i) = o;
}

// 2) W [1024][1024] f32 -> Wt bf16 [e][d] (transpose+convert), 3 weights ------
__global__ __launch_bounds__(256) void wt_kernel(
        const float* __restrict__ W0, const float* __restrict__ W1, const float* __restrict__ W2,
        u16* __restrict__ O0, u16* __restrict__ O1, u16* __restrict__ O2) {
    const float* W = blockIdx.z == 0 ? W0 : blockIdx.z == 1 ? W1 : W2;
    u16* O = blockIdx.z == 0 ? O0 : blockIdx.z == 1 ? O1 : O2;
    __shared__ float t[32][33];
    const int cx = threadIdx.x & 31, ry = threadIdx.x >> 5;
    const int d0 = blockIdx.x * 32, e0 = blockIdx.y * 32;
#pragma unroll
    for (int i = 0; i < 4; i++) t[ry + i * 8][cx] = W[(long)(d0 + ry + i * 8) * 1024 + e0 + cx];
    __syncthreads();
#pragma unroll
    for (int i = 0; i < 4; i++) O[(long)(e0 + ry + i * 8) * 1024 + d0 + cx] = f2bf(t[cx][ry + i * 8]);
}

// 3) 256xBNT 4-phase GEMM: C = A[M][K] @ Bt[N][K]^T ---------------------------
// Sync skeleton (stage slots / vmcnt gates / barriers / prologue): byte-identical
// to rounds 12/13 (verified). Round 14/15: BNT=256 path holds ALL 4 B
// col-frags in registers (bfr 2->4, +16 VGPR) — kills the Pb B re-read and
// consolidates B reads into Pa's first interval: 224 -> 192 KB LDS/kt.
// BNT=128 path (QKV/PV) unchanged from r13.
// NOTE: MODE=2's f32 epilogue bounce needs 131072 B dynamic LDS (256x128 f32),
// more than the K-loop's 98304 — allocate 131072 for PV (r14 bug).
// MODE 0: QKV fused (bias; Q,K row-major; V transposed into Vt)
// MODE 1: scores (*scale, bf16 out, batched)
// MODE 2: PV (f32 out, batched)
template <int MODE, int BNT>
__global__ __launch_bounds__(512) void gemm8_kernel(
        const u16* __restrict__ A, const u16* __restrict__ Bt,
        void* __restrict__ out0, void* __restrict__ out1, void* __restrict__ out2,
        const float* __restrict__ b0, const float* __restrict__ b1, const float* __restrict__ b2,
        int K, int N, long sAb, long sBb, long sCb, float scale)
{
    extern __shared__ u16 lds[];
    constexpr int DB = (BNT == 256) ? 32768 : 24576;  // u16 per dbuf
    constexpr int RF = (BNT == 256) ? 8 : 4;          // row frags per wave
    constexpr int AF = (BNT == 256) ? 4 : 2;          // A frags held
    const int tid = threadIdx.x, lane = tid & 63, wid = tid >> 6;
    const int wm = (BNT == 256) ? (wid >> 2) : (wid >> 1);
    const int wn = (BNT == 256) ? (wid & 3) : (wid & 1);
    const int l15 = lane & 15, hib = (lane >> 4) * 16;

    // XCD-aware bijective swizzle (all grids have nwg % 8 == 0)
    const int nbx = gridDim.x;
    const int nwg = nbx * gridDim.y;
    int lin = blockIdx.y * nbx + blockIdx.x;
    lin = (lin & 7) * (nwg >> 3) + (lin >> 3);
    const long m0 = (long)(lin / nbx) * 256;
    const long n0 = (long)(lin % nbx) * BNT;

    const u16* Ab = A + (long)blockIdx.z * sAb;
    const u16* Bb = Bt + (long)blockIdx.z * sBb;
    const long ldk = K;
    const int NT = K >> 6;          // K-tiles of 64

    // ---- staging ------------------------------------------------------------
    auto stA = [&](int dbuf, int S, int kt) {
#pragma unroll
        for (int i = 0; i < 2; ++i) {
            const int rl = tid >> 3;
            const int R  = S * 64 + rl;
            const int cb = (tid & 7) * 16;
            const int scb = cb ^ ((R & 7) << 4);        // inverse swizzle on SOURCE
            const u16* src = Ab + (m0 + i * 128 + R) * ldk + (long)kt * 64 + (scb >> 1);
            u16* dst = lds + dbuf * DB + i * 8192 + S * 4096 + wid * 512;
            gload_lds16(src, dst);
        }
    };
    auto stB = [&](int dbuf, int NHs, int kt) {   // BNT==256 only
#pragma unroll
        for (int i = 0; i < 2; ++i) {
            const int c = i * 2 + (wid >> 2);
            const int h = c >> 1, rb = (c & 1) * 64;
            const int w = (wid & 3) * 64 + lane;
            const int r32 = w >> 3;
            const int R = rb + NHs * 32 + r32;
            const int cb = (w & 7) * 16;
            const int scb = cb ^ ((R & 7) << 4);
            const u16* src = Bb + (n0 + h * 128 + R) * ldk + (long)kt * 64 + (scb >> 1);
            u16* dst = lds + dbuf * DB + 16384 + h * 8192 + (rb + NHs * 32) * 64 + (wid & 3) * 512;
            gload_lds16(src, dst);
        }
    };
    auto stB128 = [&](int dbuf, int kt) {          // BNT==128 only: one 128x64 unit
#pragma unroll
        for (int i = 0; i < 2; ++i) {
            const int R = i * 64 + (tid >> 3);
            const int cb = (tid & 7) * 16;
            const int scb = cb ^ ((R & 7) << 4);
            const u16* src = Bb + (n0 + R) * ldk + (long)kt * 64 + (scb >> 1);
            u16* dst = lds + dbuf * DB + 16384 + i * 4096 + tid * 8;
            gload_lds16(src, dst);
        }
    };

    floatx4 acc[RF][4] = {};
    short8 afr[AF][2], bfr[4][2];    // bfr holds ALL col-frags (both BNT paths)

    auto LA = [&](int dbuf, auto MHc) {
        constexpr int MH = decltype(MHc)::value;
        if constexpr (BNT == 256) {
            const char* reg = (const char*)(lds + dbuf * DB + wm * 8192);
#pragma unroll
            for (int fm = 0; fm < 4; ++fm)
#pragma unroll
                for (int ks = 0; ks < 2; ++ks) {
                    const int r = MH * 64 + fm * 16 + l15;
                    const int cb = ks * 64 + hib;
                    afr[fm][ks] = *(const short8*)(reg + r * 128 + (cb ^ ((r & 7) << 4)));
                }
        } else {
            const char* reg = (const char*)(lds + dbuf * DB);
#pragma unroll
            for (int fm = 0; fm < 2; ++fm)
#pragma unroll
                for (int ks = 0; ks < 2; ++ks) {
                    const int r = wm * 64 + MH * 32 + fm * 16 + l15;
                    const int cb = ks * 64 + hib;
                    afr[fm][ks] = *(const short8*)(reg + r * 128 + (cb ^ ((r & 7) << 4)));
                }
        }
    };
    auto LB = [&](int dbuf, auto NHc) {
        constexpr int NH = decltype(NHc)::value;
        if constexpr (BNT == 256) {
            const char* reg = (const char*)(lds + dbuf * DB + 16384 + (wn >> 1) * 8192);
#pragma unroll
            for (int fn = 0; fn < 2; ++fn)
#pragma unroll
                for (int ks = 0; ks < 2; ++ks) {
                    const int r = (wn & 1) * 64 + NH * 32 + fn * 16 + l15;
                    const int cb = ks * 64 + hib;
                    bfr[NH * 2 + fn][ks] = *(const short8*)(reg + r * 128 + (cb ^ ((r & 7) << 4)));
                }
        } else {
            const char* reg = (const char*)(lds + dbuf * DB + 16384);
#pragma unroll
            for (int fn = 0; fn < 2; ++fn)
#pragma unroll
                for (int ks = 0; ks < 2; ++ks) {
                    const int r = wn * 64 + NH * 32 + fn * 16 + l15;
                    const int cb = ks * 64 + hib;
                    bfr[NH * 2 + fn][ks] = *(const short8*)(reg + r * 128 + (cb ^ ((r & 7) << 4)));
                }
        }
    };
    auto MM = [&](auto MHc, auto NHc) {
        constexpr int MH = decltype(MHc)::value;
        constexpr int NH = decltype(NHc)::value;
        __builtin_amdgcn_s_setprio(1);
        if constexpr (BNT == 256) {
#pragma unroll
            for (int ks = 0; ks < 2; ++ks)
#pragma unroll
                for (int fm = 0; fm < 4; ++fm)
#pragma unroll
                    for (int fn = 0; fn < 2; ++fn)
                        acc[MH * 4 + fm][NH * 2 + fn] = __builtin_amdgcn_mfma_f32_16x16x32_bf16(
                            afr[fm][ks], bfr[NH * 2 + fn][ks], acc[MH * 4 + fm][NH * 2 + fn], 0, 0, 0);
        } else {
#pragma unroll
            for (int ks = 0; ks < 2; ++ks)
#pragma unroll
                for (int fm = 0; fm < 2; ++fm)
#pragma unroll
                    for (int fn = 0; fn < 2; ++fn)
                        acc[MH * 2 + fm][NH * 2 + fn] = __builtin_amdgcn_mfma_f32_16x16x32_bf16(
                            afr[fm][ks], bfr[NH * 2 + fn][ks], acc[MH * 2 + fm][NH * 2 + fn], 0, 0, 0);
        }
        __builtin_amdgcn_s_setprio(0);
    };

#define BAR() __builtin_amdgcn_s_barrier()

    // ---- prologue (identical to r12/r13) --------------------------------------
    if constexpr (BNT == 256) {
        stA(0, 0, 0); stA(0, 1, 0); stB(0, 0, 0); stB(0, 1, 0);
        stA(1, 0, 1); stB(1, 1, 1);
        asm volatile("s_waitcnt vmcnt(4)");
    } else {
        stA(0, 0, 0); stA(0, 1, 0); stB128(0, 0);
        stA(1, 0, 1);
        asm volatile("s_waitcnt vmcnt(2)");
    }
    BAR();

    // ---- main loop: one iteration = 2 K-tiles = 4 merged phases --------------
    auto pair = [&](auto LASTC, int kt0) {
        constexpr bool L = decltype(LASTC)::value;
        if constexpr (BNT == 256) {
            // Pa0 (kt0, dbuf0): read A(mh0) + BOTH B halves (held all kt)
            stA(1, 1, kt0 + 1); stB(1, 0, kt0 + 1);
            LA(0, IC(0)); LB(0, IC(0)); LB(0, IC(1));
            BAR();
            MM(IC(0), IC(0));
            MM(IC(0), IC(1));
            LA(0, IC(1));
            BAR();
            // Pb0
            if (!L) { stA(0, 0, kt0 + 2); stB(0, 1, kt0 + 2); }
            BAR();
            MM(IC(1), IC(1));
            MM(IC(1), IC(0));
            if (L) asm volatile("s_waitcnt vmcnt(0)");
            else   asm volatile("s_waitcnt vmcnt(4)");
            BAR();
            // Pa1 (kt0+1, dbuf1)
            if (!L) { stA(0, 1, kt0 + 2); stB(0, 0, kt0 + 2); }
            LA(1, IC(0)); LB(1, IC(0)); LB(1, IC(1));
            BAR();
            MM(IC(0), IC(0));
            MM(IC(0), IC(1));
            LA(1, IC(1));
            BAR();
            // Pb1
            if (!L) { stA(1, 0, kt0 + 3); stB(1, 1, kt0 + 3); }
            BAR();
            MM(IC(1), IC(1));
            MM(IC(1), IC(0));
            if (L) asm volatile("s_waitcnt vmcnt(0)");
            else   asm volatile("s_waitcnt vmcnt(4)");
            BAR();
        } else {
            // Pa0 (kt0, dbuf0): stage slots as r12; read A(mh0) + both B halves
            stA(1, 1, kt0 + 1); stB128(1, kt0 + 1);
            LA(0, IC(0)); LB(0, IC(0)); LB(0, IC(1));
            BAR();
            MM(IC(0), IC(0));
            MM(IC(0), IC(1));
            LA(0, IC(1));                 // A(mh1), overwrites afr after last use
            BAR();
            // Pb0
            if (!L) stA(0, 0, kt0 + 2);
            BAR();
            MM(IC(1), IC(1));
            MM(IC(1), IC(0));
            if (L) asm volatile("s_waitcnt vmcnt(0)");
            else   asm volatile("s_waitcnt vmcnt(2)");
            BAR();
            // Pa1 (kt0+1, dbuf1)
            if (!L) { stA(0, 1, kt0 + 2); stB128(0, kt0 + 2); }
            LA(1, IC(0)); LB(1, IC(0)); LB(1, IC(1));
            BAR();
            MM(IC(0), IC(0));
            MM(IC(0), IC(1));
            LA(1, IC(1));
            BAR();
            // Pb1
            if (!L) stA(1, 0, kt0 + 3);
            BAR();
            MM(IC(1), IC(1));
            MM(IC(1), IC(0));
            if (L) asm volatile("s_waitcnt vmcnt(0)");
            else   asm volatile("s_waitcnt vmcnt(2)");
            BAR();
        }
    };

    const int NITER = NT >> 1;
    int it = 0;
    for (; it < NITER - 1; ++it) pair(std::false_type{}, 2 * it);
    pair(std::true_type{}, 2 * it);

#undef BAR

    // ---- epilogue: swizzled LDS bounce -> coalesced global stores -----------
    // C/D frag layout: col=lane&15, row=(lane>>4)*4+j (HW-verified).
    // Wave tile: rows [wm*RF*16, +RF*16), cols [wn*64, +64) for both BNT paths.
    const int cr = (lane >> 4) * 4, cc = l15;
    const int rowbase = wm * (RF * 16), colbase = wn * 64;
    char* ldsB = (char*)lds;
    const int sel = (MODE == 0) ? (int)(n0 >> 10) : 0;
    __syncthreads();   // staging LDS fully dead
    if (MODE == 2) {
#pragma unroll
        for (int j = 0; j < 4; ++j) {
            const int col = colbase + j * 16 + cc;
#pragma unroll
            for (int i = 0; i < RF; ++i) {
                const int row = rowbase + i * 16 + cr;
#pragma unroll
                for (int jj = 0; jj < 4; ++jj)
                    *(float*)(ldsB + ((((row + jj) * BNT + col) * 4) ^ (((row + jj) & 7) << 4))) =
                        acc[i][j][jj];
            }
        }
        __syncthreads();
        constexpr int NIT = 256 * BNT / 4 / 512;       // float4 copies per thread
        float* O = (float*)out0 + (long)blockIdx.z * sCb;
#pragma unroll
        for (int i = 0; i < NIT; ++i) {
            const int g4 = tid + i * 512;
            const int row = g4 >> 5;                    // BNT=128: 32 float4 per row
            const int c4  = g4 & 31;
            float4 v = *(const float4*)(ldsB + ((g4 * 16) ^ ((row & 7) << 4)));
            *(float4*)(O + (m0 + row) * (long)N + n0 + c4 * 4) = v;
        }
    } else if (MODE == 0 && sel == 2) {
        // V: TRANSPOSED bounce -> Vt[4][1024][2048]. LDS layout [e:BNT][t:256]
        const long nc0 = n0 & 1023;
        const long b = m0 >> 11, tb = m0 & 2047;   // 2048 % 256 == 0: no crossing
#pragma unroll
        for (int j = 0; j < 4; ++j) {
            const int e = colbase + j * 16 + cc;
            const float bvv = b2[nc0 + e];
#pragma unroll
            for (int i = 0; i < RF; ++i) {
                const int t = rowbase + i * 16 + cr;
                ushort4 w;
                w.x = f2bf(acc[i][j][0] + bvv);
                w.y = f2bf(acc[i][j][1] + bvv);
                w.z = f2bf(acc[i][j][2] + bvv);
                w.w = f2bf(acc[i][j][3] + bvv);   // j contiguous in t -> 8B store
                *(ushort4*)(ldsB + (((e * 256 + t) * 2) ^ ((e & 7) << 4))) = w;
            }
        }
        __syncthreads();
        constexpr int NIT = 256 * BNT / 8 / 512;       // ushort8 copies per thread
        u16* O = (u16*)out2 + b * 1024L * 2048 + nc0 * 2048 + tb;
#pragma unroll
        for (int i = 0; i < NIT; ++i) {
            const int g8 = tid + i * 512;
            const int e  = g8 >> 5;                     // 32 ushort8 per e-row
            const int c8 = g8 & 31;
            ushort8 v = *(const ushort8*)(ldsB + ((g8 * 16) ^ ((e & 7) << 4)));
            *(ushort8*)(O + (long)e * 2048 + c8 * 8) = v;
        }
    } else {
        const float* bias = (MODE == 0) ? (sel == 0 ? b0 : b1) : nullptr;
        const long nc0 = n0 & 1023;
#pragma unroll
        for (int j = 0; j < 4; ++j) {
            const int col = colbase + j * 16 + cc;
            const float bvv = (MODE == 0) ? bias[nc0 + col] : 0.f;
#pragma unroll
            for (int i = 0; i < RF; ++i) {
                const int row = rowbase + i * 16 + cr;
#pragma unroll
                for (int jj = 0; jj < 4; ++jj) {
                    float v = acc[i][j][jj];
                    if (MODE == 1) v *= scale;
                    v += bvv;
                    *(u16*)(ldsB + ((((row + jj) * BNT + col) * 2) ^ (((row + jj) & 7) << 4))) = f2bf(v);
                }
            }
        }
        __syncthreads();
        constexpr int NIT = 256 * BNT / 8 / 512;       // ushort8 copies per thread
        constexpr int RSH = (BNT == 256) ? 5 : 4;      // 16B chunks per row
#pragma unroll
        for (int i = 0; i < NIT; ++i) {
            const int g8 = tid + i * 512;
            const int row = g8 >> RSH;
            const int c8  = g8 & ((BNT >> 3) - 1);
            ushort8 v = *(const ushort8*)(ldsB + ((g8 * 16) ^ ((row & 7) << 4)));
            if (MODE == 0) {
                u16* O = (u16*)(sel == 0 ? out0 : out1);
                *(ushort8*)(O + (m0 + row) * 1024 + nc0 + c8 * 8) = v;
            } else {
                u16* O = (u16*)out0 + (long)blockIdx.z * sCb;
                *(ushort8*)(O + (m0 + row) * (long)N + n0 + c8 * 8) = v;
            }
        }
    }
}

// 4) in-place row softmax over 2048 bf16 --------------------------------------
__global__ __launch_bounds__(256) void softmax_kernel(u16* __restrict__ S) {
    u16* p = S + (long)blockIdx.x * 2048;
    const int tid = threadIdx.x;
    union { int4 q; u16 u[8]; } in;
    in.q = *(const int4*)(p + tid * 8);
    float v[8];
#pragma unroll
    for (int i = 0; i < 8; i++) v[i] = bf2f(in.u[i]);
    float mx = v[0];
#pragma unroll
    for (int i = 1; i < 8; i++) mx = fmaxf(mx, v[i]);
#pragma unroll
    for (int off = 32; off; off >>= 1) mx = fmaxf(mx, __shfl_xor(mx, off));
    __shared__ float red[8];
    if ((tid & 63) == 0) red[tid >> 6] = mx;
    __syncthreads();
    mx = fmaxf(fmaxf(red[0], red[1]), fmaxf(red[2], red[3]));
    float s = 0.f;
#pragma unroll
    for (int i = 0; i < 8; i++) { v[i] = __expf(v[i] - mx); s += v[i]; }
#pragma unroll
    for (int off = 32; off; off >>= 1) s += __shfl_xor(s, off);
    if ((tid & 63) == 0) red[4 + (tid >> 6)] = s;
    __syncthreads();
    s = red[4] + red[5] + red[6] + red[7];
    const float inv = 1.f / s;
    union { int4 q; u16 u[8]; } out;
#pragma unroll
    for (int i = 0; i < 8; i++) out.u[i] = f2bf(v[i] * inv);
    *(int4*)(p + tid * 8) = out.q;
}

// -----------------------------------------------------------------------------
extern "C" void kernel_launch(void* const* d_in, const int* in_sizes, int n_in,
                              void* d_out, int out_size, void* d_ws, size_t ws_size,
                              hipStream_t stream) {
    const float* x  = (const float*)d_in[0];
    const float* Wq = (const float*)d_in[1];
    const float* bq = (const float*)d_in[2];
    const float* Wk = (const float*)d_in[3];
    const float* bk = (const float*)d_in[4];
    const float* Wv = (const float*)d_in[5];
    const float* bv = (const float*)d_in[6];
    float* out = (float*)d_out;

    char* ws = (char*)d_ws;
    const long MB = 1L << 20;
    u16* xb = (u16*)(ws);            // 16 MB  x bf16 [8192][1024]
    u16* wt = (u16*)(ws + 16 * MB);  // 6 MB   W{q,k,v}^T bf16 [3072][1024] stacked
    u16* Q  = (u16*)(ws + 22 * MB);  // 16 MB  [4][2048][1024]
    u16* Kb = (u16*)(ws + 38 * MB);  // 16 MB
    u16* Vt = (u16*)(ws + 54 * MB);  // 16 MB  [4][1024][2048]  (written directly by QKV)
    u16* Sc = (u16*)(ws + 70 * MB);  // 32 MB  scores/attn [4][2048][2048]

    (void)hipFuncSetAttribute((const void*)gemm8_kernel<0, 128>, hipFuncAttributeMaxDynamicSharedMemorySize, 98304);
    (void)hipFuncSetAttribute((const void*)gemm8_kernel<1, 256>, hipFuncAttributeMaxDynamicSharedMemorySize, 131072);
    (void)hipFuncSetAttribute((const void*)gemm8_kernel<2, 128>, hipFuncAttributeMaxDynamicSharedMemorySize, 131072);

    // x -> bf16
    cvt_f32_bf16_kernel<<<8192, 256, 0, stream>>>(x, xb);
    // W -> Wt bf16 (transposed, stacked)
    wt_kernel<<<dim3(32, 32, 3), 256, 0, stream>>>(Wq, Wk, Wv, wt, wt + 1024 * 1024, wt + 2 * 1024 * 1024);
    // fused QKV: [8192][1024] @ [3072][1024]^T + bias — 768 blocks = 3 exact generations.
    // Q,K row-major; V written TRANSPOSED into Vt by the epilogue bounce.
    gemm8_kernel<0, 128><<<dim3(24, 32, 1), 512, 98304, stream>>>(
        xb, wt, Q, Kb, Vt, bq, bk, bv, 1024, 3072, 0, 0, 0, 1.f);
    // scores = (Q @ K^T) / 32, bf16, batched — 256 blocks = 1 generation
    gemm8_kernel<1, 256><<<dim3(8, 8, 4), 512, 131072, stream>>>(
        Q, Kb, Sc, nullptr, nullptr, nullptr, nullptr, nullptr,
        1024, 2048, 2048L * 1024, 2048L * 1024, 2048L * 2048, 0.03125f);
    // softmax rows, in place
    softmax_kernel<<<8192, 256, 0, stream>>>(Sc);
    // out = attn @ V, f32 out, batched — 256 blocks = 1 generation
    // (MODE=2 f32 epilogue bounce needs 131072 B dynamic LDS — NOT 98304)
    gemm8_kernel<2, 128><<<dim3(8, 8, 4), 512, 131072, stream>>>(
        Sc, Vt, out, nullptr, nullptr, nullptr, nullptr, nullptr,
        2048, 1024, 2048L * 2048, 1024L * 2048, 2048L * 1024, 1.f);
}

// Round 16
// 165.737 us; speedup vs baseline: 1.0155x; 1.0155x over previous
//
#include <hip/hip_runtime.h>
#include <stdint.h>
#include <type_traits>

typedef unsigned short u16;
using short8  = __attribute__((ext_vector_type(8))) short;
using ushort8 = __attribute__((ext_vector_type(8))) unsigned short;
using floatx4 = __attribute__((ext_vector_type(4))) float;

#define IC(n) (std::integral_constant<int, (n)>())

__device__ __forceinline__ u16 f2bf(float f) {
    unsigned u = __float_as_uint(f);
    u += 0x7fff + ((u >> 16) & 1);   // round-to-nearest-even
    return (u16)(u >> 16);
}
__device__ __forceinline__ float bf2f(u16 h) {
    return __uint_as_float(((unsigned)h) << 16);
}

// async global->LDS, 16B per lane (global_load_lds_dwordx4)
__device__ __forceinline__ void gload_lds16(const void* g, void* l) {
    auto gp = reinterpret_cast<const __attribute__((address_space(1))) unsigned int*>(
        reinterpret_cast<uintptr_t>(g));
    auto lp = reinterpret_cast<__attribute__((address_space(3))) unsigned int*>(
        reinterpret_cast<uintptr_t>(l));
    __builtin_amdgcn_global_load_lds(gp, lp, 16, 0, 0);
}

// 1) merged preprocessing: blocks [0,8192) cvt x f32->bf16; [8192,11264) W^T --
__global__ __launch_bounds__(256) void prep_kernel(
        const float* __restrict__ x, u16* __restrict__ xb,
        const float* __restrict__ W0, const float* __restrict__ W1, const float* __restrict__ W2,
        u16* __restrict__ O0, u16* __restrict__ O1, u16* __restrict__ O2) {
    __shared__ float t[32][33];
    const int bid = blockIdx.x;
    if (bid < 8192) {
        long i = ((long)bid * 256 + threadIdx.x) * 4;
        float4 v = *(const float4*)(x + i);
        ushort4 o;
        o.x = f2bf(v.x); o.y = f2bf(v.y); o.z = f2bf(v.z); o.w = f2bf(v.w);
        *(ushort4*)(xb + i) = o;
    } else {
        const int b = bid - 8192;           // 0..3071
        const int z = b >> 10;              // weight 0..2
        const int r = b & 1023;
        const int d0 = (r & 31) * 32, e0 = (r >> 5) * 32;
        const float* W = z == 0 ? W0 : z == 1 ? W1 : W2;
        u16* O = z == 0 ? O0 : z == 1 ? O1 : O2;
        const int cx = threadIdx.x & 31, ry = threadIdx.x >> 5;
#pragma unroll
        for (int i = 0; i < 4; i++) t[ry + i * 8][cx] = W[(long)(d0 + ry + i * 8) * 1024 + e0 + cx];
        __syncthreads();
#pragma unroll
        for (int i = 0; i < 4; i++) O[(long)(e0 + ry + i * 8) * 1024 + d0 + cx] = f2bf(t[cx][ry + i * 8]);
    }
}

// 2) 256xBNT 4-phase GEMM: C = A[M][K] @ Bt[N][K]^T ---------------------------
// EXACT round-13 verified configuration (167.0 us):
//  - sync skeleton (stage slots / vmcnt gates / barriers / prologue) = r12
//  - BNT=128 path: 4m x 2n wave grid (wave tile 64x64), both B halves in regs
//  - BNT=256 path: 2m x 4n, bfr[2], per-phase B reads (r13 schedule)
//  - coalesced epilogues via swizzled LDS bounce; MODE0 V written transposed
// MODE 0: QKV fused (bias; Q,K row-major; V transposed into Vt)
// MODE 1: scores (*scale, bf16 out, batched)
// MODE 2: PV (f32 out, batched; needs 131072 B dynamic LDS for f32 bounce)
template <int MODE, int BNT>
__global__ __launch_bounds__(512) void gemm8_kernel(
        const u16* __restrict__ A, const u16* __restrict__ Bt,
        void* __restrict__ out0, void* __restrict__ out1, void* __restrict__ out2,
        const float* __restrict__ b0, const float* __restrict__ b1, const float* __restrict__ b2,
        int K, int N, long sAb, long sBb, long sCb, float scale)
{
    extern __shared__ u16 lds[];
    constexpr int DB = (BNT == 256) ? 32768 : 24576;  // u16 per dbuf
    constexpr int RF = (BNT == 256) ? 8 : 4;          // row frags per wave
    constexpr int AF = (BNT == 256) ? 4 : 2;          // A frags held
    constexpr int BF = (BNT == 256) ? 2 : 4;          // B frags held
    const int tid = threadIdx.x, lane = tid & 63, wid = tid >> 6;
    const int wm = (BNT == 256) ? (wid >> 2) : (wid >> 1);
    const int wn = (BNT == 256) ? (wid & 3) : (wid & 1);
    const int l15 = lane & 15, hib = (lane >> 4) * 16;

    // XCD-aware bijective swizzle (all grids have nwg % 8 == 0)
    const int nbx = gridDim.x;
    const int nwg = nbx * gridDim.y;
    int lin = blockIdx.y * nbx + blockIdx.x;
    lin = (lin & 7) * (nwg >> 3) + (lin >> 3);
    const long m0 = (long)(lin / nbx) * 256;
    const long n0 = (long)(lin % nbx) * BNT;

    const u16* Ab = A + (long)blockIdx.z * sAb;
    const u16* Bb = Bt + (long)blockIdx.z * sBb;
    const long ldk = K;
    const int NT = K >> 6;          // K-tiles of 64

    // ---- staging ------------------------------------------------------------
    auto stA = [&](int dbuf, int S, int kt) {
#pragma unroll
        for (int i = 0; i < 2; ++i) {
            const int rl = tid >> 3;
            const int R  = S * 64 + rl;
            const int cb = (tid & 7) * 16;
            const int scb = cb ^ ((R & 7) << 4);        // inverse swizzle on SOURCE
            const u16* src = Ab + (m0 + i * 128 + R) * ldk + (long)kt * 64 + (scb >> 1);
            u16* dst = lds + dbuf * DB + i * 8192 + S * 4096 + wid * 512;
            gload_lds16(src, dst);
        }
    };
    auto stB = [&](int dbuf, int NHs, int kt) {   // BNT==256 only
#pragma unroll
        for (int i = 0; i < 2; ++i) {
            const int c = i * 2 + (wid >> 2);
            const int h = c >> 1, rb = (c & 1) * 64;
            const int w = (wid & 3) * 64 + lane;
            const int r32 = w >> 3;
            const int R = rb + NHs * 32 + r32;
            const int cb = (w & 7) * 16;
            const int scb = cb ^ ((R & 7) << 4);
            const u16* src = Bb + (n0 + h * 128 + R) * ldk + (long)kt * 64 + (scb >> 1);
            u16* dst = lds + dbuf * DB + 16384 + h * 8192 + (rb + NHs * 32) * 64 + (wid & 3) * 512;
            gload_lds16(src, dst);
        }
    };
    auto stB128 = [&](int dbuf, int kt) {          // BNT==128 only: one 128x64 unit
#pragma unroll
        for (int i = 0; i < 2; ++i) {
            const int R = i * 64 + (tid >> 3);
            const int cb = (tid & 7) * 16;
            const int scb = cb ^ ((R & 7) << 4);
            const u16* src = Bb + (n0 + R) * ldk + (long)kt * 64 + (scb >> 1);
            u16* dst = lds + dbuf * DB + 16384 + i * 4096 + tid * 8;
            gload_lds16(src, dst);
        }
    };

    floatx4 acc[RF][4] = {};
    short8 afr[AF][2], bfr[BF][2];

    auto LA = [&](int dbuf, auto MHc) {
        constexpr int MH = decltype(MHc)::value;
        if constexpr (BNT == 256) {
            const char* reg = (const char*)(lds + dbuf * DB + wm * 8192);
#pragma unroll
            for (int fm = 0; fm < 4; ++fm)
#pragma unroll
                for (int ks = 0; ks < 2; ++ks) {
                    const int r = MH * 64 + fm * 16 + l15;
                    const int cb = ks * 64 + hib;
                    afr[fm][ks] = *(const short8*)(reg + r * 128 + (cb ^ ((r & 7) << 4)));
                }
        } else {
            const char* reg = (const char*)(lds + dbuf * DB);
#pragma unroll
            for (int fm = 0; fm < 2; ++fm)
#pragma unroll
                for (int ks = 0; ks < 2; ++ks) {
                    const int r = wm * 64 + MH * 32 + fm * 16 + l15;
                    const int cb = ks * 64 + hib;
                    afr[fm][ks] = *(const short8*)(reg + r * 128 + (cb ^ ((r & 7) << 4)));
                }
        }
    };
    auto LB = [&](int dbuf, auto NHc) {
        constexpr int NH = decltype(NHc)::value;
        if constexpr (BNT == 256) {
            const char* reg = (const char*)(lds + dbuf * DB + 16384 + (wn >> 1) * 8192);
#pragma unroll
            for (int fn = 0; fn < 2; ++fn)
#pragma unroll
                for (int ks = 0; ks < 2; ++ks) {
                    const int r = (wn & 1) * 64 + NH * 32 + fn * 16 + l15;
                    const int cb = ks * 64 + hib;
                    bfr[fn][ks] = *(const short8*)(reg + r * 128 + (cb ^ ((r & 7) << 4)));
                }
        } else {
            const char* reg = (const char*)(lds + dbuf * DB + 16384);
#pragma unroll
            for (int fn = 0; fn < 2; ++fn)
#pragma unroll
                for (int ks = 0; ks < 2; ++ks) {
                    const int r = wn * 64 + NH * 32 + fn * 16 + l15;
                    const int cb = ks * 64 + hib;
                    bfr[NH * 2 + fn][ks] = *(const short8*)(reg + r * 128 + (cb ^ ((r & 7) << 4)));
                }
        }
    };
    auto MM = [&](auto MHc, auto NHc) {
        constexpr int MH = decltype(MHc)::value;
        constexpr int NH = decltype(NHc)::value;
        __builtin_amdgcn_s_setprio(1);
        if constexpr (BNT == 256) {
#pragma unroll
            for (int ks = 0; ks < 2; ++ks)
#pragma unroll
                for (int fm = 0; fm < 4; ++fm)
#pragma unroll
                    for (int fn = 0; fn < 2; ++fn)
                        acc[MH * 4 + fm][NH * 2 + fn] = __builtin_amdgcn_mfma_f32_16x16x32_bf16(
                            afr[fm][ks], bfr[fn][ks], acc[MH * 4 + fm][NH * 2 + fn], 0, 0, 0);
        } else {
#pragma unroll
            for (int ks = 0; ks < 2; ++ks)
#pragma unroll
                for (int fm = 0; fm < 2; ++fm)
#pragma unroll
                    for (int fn = 0; fn < 2; ++fn)
                        acc[MH * 2 + fm][NH * 2 + fn] = __builtin_amdgcn_mfma_f32_16x16x32_bf16(
                            afr[fm][ks], bfr[NH * 2 + fn][ks], acc[MH * 2 + fm][NH * 2 + fn], 0, 0, 0);
        }
        __builtin_amdgcn_s_setprio(0);
    };

#define BAR() __builtin_amdgcn_s_barrier()

    // ---- prologue (identical to r12/r13) --------------------------------------
    if constexpr (BNT == 256) {
        stA(0, 0, 0); stA(0, 1, 0); stB(0, 0, 0); stB(0, 1, 0);
        stA(1, 0, 1); stB(1, 1, 1);
        asm volatile("s_waitcnt vmcnt(4)");
    } else {
        stA(0, 0, 0); stA(0, 1, 0); stB128(0, 0);
        stA(1, 0, 1);
        asm volatile("s_waitcnt vmcnt(2)");
    }
    BAR();

    // ---- main loop: one iteration = 2 K-tiles = 4 merged phases --------------
    auto pair = [&](auto LASTC, int kt0) {
        constexpr bool L = decltype(LASTC)::value;
        if constexpr (BNT == 256) {
            stA(1, 1, kt0 + 1); stB(1, 0, kt0 + 1);
            LA(0, IC(0)); LB(0, IC(0));
            BAR();
            MM(IC(0), IC(0));
            LB(0, IC(1));
            MM(IC(0), IC(1));
            LA(0, IC(1));
            BAR();
            if (!L) { stA(0, 0, kt0 + 2); stB(0, 1, kt0 + 2); }
            BAR();
            MM(IC(1), IC(1));
            LB(0, IC(0));
            MM(IC(1), IC(0));
            if (L) asm volatile("s_waitcnt vmcnt(0)");
            else   asm volatile("s_waitcnt vmcnt(4)");
            BAR();
            if (!L) { stA(0, 1, kt0 + 2); stB(0, 0, kt0 + 2); }
            LA(1, IC(0)); LB(1, IC(0));
            BAR();
            MM(IC(0), IC(0));
            LB(1, IC(1));
            MM(IC(0), IC(1));
            LA(1, IC(1));
            BAR();
            if (!L) { stA(1, 0, kt0 + 3); stB(1, 1, kt0 + 3); }
            BAR();
            MM(IC(1), IC(1));
            LB(1, IC(0));
            MM(IC(1), IC(0));
            if (L) asm volatile("s_waitcnt vmcnt(0)");
            else   asm volatile("s_waitcnt vmcnt(4)");
            BAR();
        } else {
            // Pa0 (kt0, dbuf0): stage slots as r12; read A(mh0) + both B halves
            stA(1, 1, kt0 + 1); stB128(1, kt0 + 1);
            LA(0, IC(0)); LB(0, IC(0)); LB(0, IC(1));
            BAR();
            MM(IC(0), IC(0));
            MM(IC(0), IC(1));
            LA(0, IC(1));                 // A(mh1), overwrites afr after last use
            BAR();
            // Pb0
            if (!L) stA(0, 0, kt0 + 2);
            BAR();
            MM(IC(1), IC(1));
            MM(IC(1), IC(0));
            if (L) asm volatile("s_waitcnt vmcnt(0)");
            else   asm volatile("s_waitcnt vmcnt(2)");
            BAR();
            // Pa1 (kt0+1, dbuf1)
            if (!L) { stA(0, 1, kt0 + 2); stB128(0, kt0 + 2); }
            LA(1, IC(0)); LB(1, IC(0)); LB(1, IC(1));
            BAR();
            MM(IC(0), IC(0));
            MM(IC(0), IC(1));
            LA(1, IC(1));
            BAR();
            // Pb1
            if (!L) stA(1, 0, kt0 + 3);
            BAR();
            MM(IC(1), IC(1));
            MM(IC(1), IC(0));
            if (L) asm volatile("s_waitcnt vmcnt(0)");
            else   asm volatile("s_waitcnt vmcnt(2)");
            BAR();
        }
    };

    const int NITER = NT >> 1;
    int it = 0;
    for (; it < NITER - 1; ++it) pair(std::false_type{}, 2 * it);
    pair(std::true_type{}, 2 * it);

#undef BAR

    // ---- epilogue: swizzled LDS bounce -> coalesced global stores -----------
    // C/D frag layout: col=lane&15, row=(lane>>4)*4+j (HW-verified).
    // Wave tile: rows [wm*RF*16, +RF*16), cols [wn*64, +64) for both BNT paths.
    const int cr = (lane >> 4) * 4, cc = l15;
    const int rowbase = wm * (RF * 16), colbase = wn * 64;
    char* ldsB = (char*)lds;
    const int sel = (MODE == 0) ? (int)(n0 >> 10) : 0;
    __syncthreads();   // staging LDS fully dead
    if (MODE == 2) {
#pragma unroll
        for (int j = 0; j < 4; ++j) {
            const int col = colbase + j * 16 + cc;
#pragma unroll
            for (int i = 0; i < RF; ++i) {
                const int row = rowbase + i * 16 + cr;
#pragma unroll
                for (int jj = 0; jj < 4; ++jj)
                    *(float*)(ldsB + ((((row + jj) * BNT + col) * 4) ^ (((row + jj) & 7) << 4))) =
                        acc[i][j][jj];
            }
        }
        __syncthreads();
        constexpr int NIT = 256 * BNT / 4 / 512;       // float4 copies per thread
        float* O = (float*)out0 + (long)blockIdx.z * sCb;
#pragma unroll
        for (int i = 0; i < NIT; ++i) {
            const int g4 = tid + i * 512;
            const int row = g4 >> 5;                    // BNT=128: 32 float4 per row
            const int c4  = g4 & 31;
            float4 v = *(const float4*)(ldsB + ((g4 * 16) ^ ((row & 7) << 4)));
            *(float4*)(O + (m0 + row) * (long)N + n0 + c4 * 4) = v;
        }
    } else if (MODE == 0 && sel == 2) {
        // V: TRANSPOSED bounce -> Vt[4][1024][2048]. LDS layout [e:BNT][t:256]
        const long nc0 = n0 & 1023;
        const long b = m0 >> 11, tb = m0 & 2047;   // 2048 % 256 == 0: no crossing
#pragma unroll
        for (int j = 0; j < 4; ++j) {
            const int e = colbase + j * 16 + cc;
            const float bvv = b2[nc0 + e];
#pragma unroll
            for (int i = 0; i < RF; ++i) {
                const int t = rowbase + i * 16 + cr;
                ushort4 w;
                w.x = f2bf(acc[i][j][0] + bvv);
                w.y = f2bf(acc[i][j][1] + bvv);
                w.z = f2bf(acc[i][j][2] + bvv);
                w.w = f2bf(acc[i][j][3] + bvv);   // j contiguous in t -> 8B store
                *(ushort4*)(ldsB + (((e * 256 + t) * 2) ^ ((e & 7) << 4))) = w;
            }
        }
        __syncthreads();
        constexpr int NIT = 256 * BNT / 8 / 512;       // ushort8 copies per thread
        u16* O = (u16*)out2 + b * 1024L * 2048 + nc0 * 2048 + tb;
#pragma unroll
        for (int i = 0; i < NIT; ++i) {
            const int g8 = tid + i * 512;
            const int e  = g8 >> 5;                     // 32 ushort8 per e-row
            const int c8 = g8 & 31;
            ushort8 v = *(const ushort8*)(ldsB + ((g8 * 16) ^ ((e & 7) << 4)));
            *(ushort8*)(O + (long)e * 2048 + c8 * 8) = v;
        }
    } else {
        const float* bias = (MODE == 0) ? (sel == 0 ? b0 : b1) : nullptr;
        const long nc0 = n0 & 1023;
#pragma unroll
        for (int j = 0; j < 4; ++j) {
            const int col = colbase + j * 16 + cc;
            const float bvv = (MODE == 0) ? bias[nc0 + col] : 0.f;
#pragma unroll
            for (int i = 0; i < RF; ++i) {
                const int row = rowbase + i * 16 + cr;
#pragma unroll
                for (int jj = 0; jj < 4; ++jj) {
                    float v = acc[i][j][jj];
                    if (MODE == 1) v *= scale;
                    v += bvv;
                    *(u16*)(ldsB + ((((row + jj) * BNT + col) * 2) ^ (((row + jj) & 7) << 4))) = f2bf(v);
                }
            }
        }
        __syncthreads();
        constexpr int NIT = 256 * BNT / 8 / 512;       // ushort8 copies per thread
        constexpr int RSH = (BNT == 256) ? 5 : 4;      // 16B chunks per row
#pragma unroll
        for (int i = 0; i < NIT; ++i) {
            const int g8 = tid + i * 512;
            const int row = g8 >> RSH;
            const int c8  = g8 & ((BNT >> 3) - 1);
            ushort8 v = *(const ushort8*)(ldsB + ((g8 * 16) ^ ((row & 7) << 4)));
            if (MODE == 0) {
                u16* O = (u16*)(sel == 0 ? out0 : out1);
                *(ushort8*)(O + (m0 + row) * 1024 + nc0 + c8 * 8) = v;
            } else {
                u16* O = (u16*)out0 + (long)blockIdx.z * sCb;
                *(ushort8*)(O + (m0 + row) * (long)N + n0 + c8 * 8) = v;
            }
        }
    }
}

// 3) in-place row softmax over 2048 bf16 --------------------------------------
__global__ __launch_bounds__(256) void softmax_kernel(u16* __restrict__ S) {
    u16* p = S + (long)blockIdx.x * 2048;
    const int tid = threadIdx.x;
    union { int4 q; u16 u[8]; } in;
    in.q = *(const int4*)(p + tid * 8);
    float v[8];
#pragma unroll
    for (int i = 0; i < 8; i++) v[i] = bf2f(in.u[i]);
    float mx = v[0];
#pragma unroll
    for (int i = 1; i < 8; i++) mx = fmaxf(mx, v[i]);
#pragma unroll
    for (int off = 32; off; off >>= 1) mx = fmaxf(mx, __shfl_xor(mx, off));
    __shared__ float red[8];
    if ((tid & 63) == 0) red[tid >> 6] = mx;
    __syncthreads();
    mx = fmaxf(fmaxf(red[0], red[1]), fmaxf(red[2], red[3]));
    float s = 0.f;
#pragma unroll
    for (int i = 0; i < 8; i++) { v[i] = __expf(v[i] - mx); s += v[i]; }
#pragma unroll
    for (int off = 32; off; off >>= 1) s += __shfl_xor(s, off);
    if ((tid & 63) == 0) red[4 + (tid >> 6)] = s;
    __syncthreads();
    s = red[4] + red[5] + red[6] + red[7];
    const float inv = 1.f / s;
    union { int4 q; u16 u[8]; } out;
#pragma unroll
    for (int i = 0; i < 8; i++) out.u[i] = f2bf(v[i] * inv);
    *(int4*)(p + tid * 8) = out.q;
}

// -----------------------------------------------------------------------------
extern "C" void kernel_launch(void* const* d_in, const int* in_sizes, int n_in,
                              void* d_out, int out_size, void* d_ws, size_t ws_size,
                              hipStream_t stream) {
    const float* x  = (const float*)d_in[0];
    const float* Wq = (const float*)d_in[1];
    const float* bq = (const float*)d_in[2];
    const float* Wk = (const float*)d_in[3];
    const float* bk = (const float*)d_in[4];
    const float* Wv = (const float*)d_in[5];
    const float* bv = (const float*)d_in[6];
    float* out = (float*)d_out;

    char* ws = (char*)d_ws;
    const long MB = 1L << 20;
    u16* xb = (u16*)(ws);            // 16 MB  x bf16 [8192][1024]
    u16* wt = (u16*)(ws + 16 * MB);  // 6 MB   W{q,k,v}^T bf16 [3072][1024] stacked
    u16* Q  = (u16*)(ws + 22 * MB);  // 16 MB  [4][2048][1024]
    u16* Kb = (u16*)(ws + 38 * MB);  // 16 MB
    u16* Vt = (u16*)(ws + 54 * MB);  // 16 MB  [4][1024][2048]  (written directly by QKV)
    u16* Sc = (u16*)(ws + 70 * MB);  // 32 MB  scores/attn [4][2048][2048]

    (void)hipFuncSetAttribute((const void*)gemm8_kernel<0, 128>, hipFuncAttributeMaxDynamicSharedMemorySize, 98304);
    (void)hipFuncSetAttribute((const void*)gemm8_kernel<1, 256>, hipFuncAttributeMaxDynamicSharedMemorySize, 131072);
    (void)hipFuncSetAttribute((const void*)gemm8_kernel<2, 128>, hipFuncAttributeMaxDynamicSharedMemorySize, 131072);

    // merged: x -> bf16  +  W -> Wt bf16 (transposed, stacked)
    prep_kernel<<<11264, 256, 0, stream>>>(
        x, xb, Wq, Wk, Wv, wt, wt + 1024 * 1024, wt + 2 * 1024 * 1024);
    // fused QKV: [8192][1024] @ [3072][1024]^T + bias — 768 blocks = 3 exact generations.
    // Q,K row-major; V written TRANSPOSED into Vt by the epilogue bounce.
    gemm8_kernel<0, 128><<<dim3(24, 32, 1), 512, 98304, stream>>>(
        xb, wt, Q, Kb, Vt, bq, bk, bv, 1024, 3072, 0, 0, 0, 1.f);
    // scores = (Q @ K^T) / 32, bf16, batched — 256 blocks = 1 generation
    gemm8_kernel<1, 256><<<dim3(8, 8, 4), 512, 131072, stream>>>(
        Q, Kb, Sc, nullptr, nullptr, nullptr, nullptr, nullptr,
        1024, 2048, 2048L * 1024, 2048L * 1024, 2048L * 2048, 0.03125f);
    // softmax rows, in place
    softmax_kernel<<<8192, 256, 0, stream>>>(Sc);
    // out = attn @ V, f32 out, batched — 256 blocks = 1 generation
    // (MODE=2 f32 epilogue bounce needs 131072 B dynamic LDS)
    gemm8_kernel<2, 128><<<dim3(8, 8, 4), 512, 131072, stream>>>(
        Sc, Vt, out, nullptr, nullptr, nullptr, nullptr, nullptr,
        2048, 1024, 2048L * 2048, 1024L * 2048, 2048L * 1024, 1.f);
}